// Round 2
// baseline (1067.772 us; speedup 1.0000x reference)
//
#include <hip/hip_runtime.h>
#include <stdint.h>

#define T_TOKENS 8192
#define DDIM 2048
#define FDIM 4096
#define NEXP 8
#define MAXTILES 72   // 128-row tiles: max 64 full + 7 ragged < 72

typedef __attribute__((ext_vector_type(8))) short bf16x8;
typedef __attribute__((ext_vector_type(4))) float f32x4;

// round-to-nearest-even fp32 -> bf16 (finite inputs)
__device__ __forceinline__ unsigned short f2bf(float f) {
  unsigned int u = __float_as_uint(f);
  unsigned int r = (u + 0x7FFFu + ((u >> 16) & 1u)) >> 16;
  return (unsigned short)r;
}

__global__ void k_assign(const float* __restrict__ logits,
                         int* __restrict__ assign,
                         int* __restrict__ counts) {
  int t = blockIdx.x * blockDim.x + threadIdx.x;
  if (t >= T_TOKENS) return;
  const float* l = logits + (size_t)t * NEXP;
  float bv = l[0]; int be = 0;
#pragma unroll
  for (int e = 1; e < NEXP; ++e) {
    float v = l[e];
    if (v > bv) { bv = v; be = e; }   // strict > : first-max tiebreak like jnp.argmax
  }
  assign[t] = be;
  atomicAdd(&counts[be], 1);
}

// offsets + tile table (128-row tiles, shared by both gemms)
__global__ void k_scan(const int* __restrict__ counts,
                       int* __restrict__ offsets,
                       int* __restrict__ tile_e,
                       int* __restrict__ tile_rb,
                       int* __restrict__ ntiles) {
  if (threadIdx.x == 0) {
    int acc = 0, nt = 0;
    for (int e = 0; e < NEXP; ++e) {
      offsets[e] = acc;
      int c = counts[e];
      acc += c;
      int t = (c + 127) >> 7;
      for (int i = 0; i < t; ++i) { tile_e[nt] = e; tile_rb[nt] = i; ++nt; }
    }
    ntiles[0] = nt;
  }
}

__global__ void k_place(const int* __restrict__ assign,
                        const int* __restrict__ offsets,
                        int* __restrict__ cursors,
                        int* __restrict__ perm) {
  int t = blockIdx.x * blockDim.x + threadIdx.x;
  if (t >= T_TOKENS) return;
  int e = assign[t];
  int pos = atomicAdd(&cursors[e], 1);
  perm[offsets[e] + pos] = t;
}

// gather tokens into bucket order, cast fp32 -> bf16 (grid-stride)
__global__ void k_gather_x(const float* __restrict__ x,
                           const int* __restrict__ perm,
                           unsigned short* __restrict__ xg) {
  const int total = T_TOKENS * (DDIM / 4);
  const int stride = gridDim.x * blockDim.x;
  for (int idx = blockIdx.x * blockDim.x + threadIdx.x; idx < total; idx += stride) {
    int slot = idx / (DDIM / 4);
    int c4 = idx - slot * (DDIM / 4);
    int tok = perm[slot];
    float4 v = ((const float4*)(x + (size_t)tok * DDIM))[c4];
    ushort4 o;
    o.x = f2bf(v.x); o.y = f2bf(v.y); o.z = f2bf(v.z); o.w = f2bf(v.w);
    ((ushort4*)(xg + (size_t)slot * DDIM))[c4] = o;
  }
}

// both weight casts in one grid-stride kernel
__global__ void k_cast2(const float* __restrict__ s1, const float* __restrict__ s2,
                        unsigned short* __restrict__ d1, unsigned short* __restrict__ d2,
                        int n4) {
  const int stride = gridDim.x * blockDim.x;
  for (int i = blockIdx.x * blockDim.x + threadIdx.x; i < 2 * n4; i += stride) {
    float4 v;
    if (i < n4) v = ((const float4*)s1)[i];
    else        v = ((const float4*)s2)[i - n4];
    ushort4 o;
    o.x = f2bf(v.x); o.y = f2bf(v.y); o.z = f2bf(v.z); o.w = f2bf(v.w);
    if (i < n4) ((ushort4*)d1)[i] = o;
    else        ((ushort4*)d2)[i - n4] = o;
  }
}

__device__ __forceinline__ void glds(const unsigned short* g, unsigned short* l) {
  __builtin_amdgcn_global_load_lds(
      (const __attribute__((address_space(1))) void*)g,
      (__attribute__((address_space(3))) void*)l, 16, 0, 0);
}

// Grouped GEMM, BM=128 x BN=256, BK=32, 8 waves (2M x 4N), wave output 64x64.
// Ring-3 LDS (72 KiB) -> 2 blocks/CU: co-resident blocks de-lockstep the
// barriers (one computes while the other waits) and halve the makespan
// quantization (~1056/528 items on 512 slots vs 528 on 256).
// Per slice (one phase): ds_read 8 frags -> issue 3 glds (slice ks+2) ->
// vmcnt(3) [slice ks+1 landed, ks+2 in flight] -> barrier -> lgkmcnt(0) ->
// sched_barrier -> setprio(1) 16xMFMA setprio(0) -> barrier.
// XOR k-chunk swizzle both-sides (pre-swizzled global src + swizzled ds_read).
template<bool FIRST>
__launch_bounds__(512, 4)
__global__ void k_gemm(const unsigned short* __restrict__ Ap,
                       const unsigned short* __restrict__ Bw,
                       unsigned short* __restrict__ Hout,
                       float* __restrict__ Out,
                       const int* __restrict__ offsets,
                       const int* __restrict__ counts,
                       const int* __restrict__ perm,
                       const int* __restrict__ tile_e,
                       const int* __restrict__ tile_rb,
                       const int* __restrict__ ntiles) {
  constexpr int K   = FIRST ? DDIM : FDIM;   // 2048 : 4096
  constexpr int N   = FIRST ? FDIM : DDIM;   // 4096 : 2048
  constexpr int NS  = K / 32;                // 64 : 128
  constexpr int ASL = 128 * 32;              // A slice shorts (8 KB)
  constexpr int BSL = 256 * 32;              // B slice shorts (16 KB)

  const int ty = blockIdx.y;
  if (ty >= ntiles[0]) return;
  const int e   = tile_e[ty];
  const int rb  = tile_rb[ty] << 7;
  const int off = offsets[e];
  const int Me  = counts[e];
  const int cb  = blockIdx.x << 8;           // 256 output cols per block

  extern __shared__ unsigned short sm[];
  unsigned short* At = sm;                   // 3 * ASL
  unsigned short* Bt = sm + 3 * ASL;         // 3 * BSL   (72 KiB total)

  const int tid  = threadIdx.x;
  const int wave = tid >> 6;
  const int lane = tid & 63;
  const int wr   = wave >> 2;                // 0..1  (M)
  const int wc   = wave & 3;                 // 0..3  (N)

  // staging map: thread -> row tq = tid>>2, k-chunk pos tid&3, with source
  // pre-swizzle: global chunk = pos ^ ((row>>1)&3)
  const int tq  = tid >> 2;
  const int kd8 = (((tid & 3) ^ ((tid >> 3) & 3)) << 3);

  int ar = rb + tq; if (ar >= Me) ar = Me - 1;   // clamp ragged M; masked in epilogue
  const unsigned short* gA  = Ap + (size_t)(off + ar) * K + kd8;
  const unsigned short* gB0 = Bw + (size_t)e * N * K + (size_t)(cb + tq) * K + kd8;
  const unsigned short* gB1 = gB0 + (size_t)128 * K;

  // wave-uniform LDS stage bases (glds adds lane*16B itself): wave w -> rows w*16..
  const int dlo = wave * 512;                // shorts

  // prologue: issue slices 0,1 (3 loads each, oldest-first), wait slice 0 landed
#pragma unroll
  for (int s = 0; s < 2; ++s) {
    glds(gA  + s * 32, At + s * ASL + dlo);
    glds(gB0 + s * 32, Bt + s * BSL + dlo);
    glds(gB1 + s * 32, Bt + s * BSL + dlo + 128 * 32);
  }
  asm volatile("s_waitcnt vmcnt(3)" ::: "memory");
  __builtin_amdgcn_s_barrier();
  asm volatile("" ::: "memory");

  // read-side fragment offsets (shorts), swizzled k-chunk
  const int kswz8 = (((lane >> 4) ^ ((lane >> 1) & 3)) << 3);
  const int aoff  = (wr * 64 + (lane & 15)) * 32 + kswz8;
  const int boff  = (wc * 64 + (lane & 15)) * 32 + kswz8;

  f32x4 acc[4][4] = {};
  int cur = 0, pre = 2;
  for (int ks = 0; ks < NS; ++ks) {
    int ka = ks + 2; if (ka >= NS) ka -= NS;   // dummy wrap keeps vmcnt invariant
    const int ko = ka * 32;
    const unsigned short* Ac = At + cur * ASL + aoff;
    const unsigned short* Bc = Bt + cur * BSL + boff;

    bf16x8 af[4], bf[4];
#pragma unroll
    for (int m = 0; m < 4; ++m) af[m] = *(const bf16x8*)(Ac + m * 512);
#pragma unroll
    for (int n = 0; n < 4; ++n) bf[n] = *(const bf16x8*)(Bc + n * 512);

    glds(gA  + ko, At + pre * ASL + dlo);
    glds(gB0 + ko, Bt + pre * BSL + dlo);
    glds(gB1 + ko, Bt + pre * BSL + dlo + 128 * 32);

    asm volatile("s_waitcnt vmcnt(3)" ::: "memory");   // slice ks+1 landed; ks+2 in flight
    __builtin_amdgcn_s_barrier();
    asm volatile("s_waitcnt lgkmcnt(0)" ::: "memory");
    __builtin_amdgcn_sched_barrier(0);
    __builtin_amdgcn_s_setprio(1);
#pragma unroll
    for (int m = 0; m < 4; ++m)
#pragma unroll
      for (int n = 0; n < 4; ++n)
        acc[m][n] = __builtin_amdgcn_mfma_f32_16x16x32_bf16(af[m], bf[n], acc[m][n], 0, 0, 0);
    __builtin_amdgcn_s_setprio(0);
    __builtin_amdgcn_s_barrier();

    cur = (cur == 2) ? 0 : cur + 1;
    pre = (pre == 2) ? 0 : pre + 1;
  }

  // epilogue: C/D layout col = lane&15, row = (lane>>4)*4 + reg
  const int ccol = lane & 15;
  const int cr0 = (lane >> 4) * 4;
  const int colbase = cb + wc * 64;
#pragma unroll
  for (int i = 0; i < 4; ++i) {
#pragma unroll
    for (int r = 0; r < 4; ++r) {
      int row = rb + wr * 64 + i * 16 + cr0 + r;
      if (row < Me) {
        if constexpr (FIRST) {
          unsigned short* hrow = Hout + (size_t)(off + row) * N;
#pragma unroll
          for (int j = 0; j < 4; ++j) {
            float v = acc[i][j][r];
            float s = v / (1.0f + __expf(-v));   // silu
            hrow[colbase + j * 16 + ccol] = f2bf(s);
          }
        } else {
          int tok = perm[off + row];
          float* orow = Out + (size_t)tok * N;
#pragma unroll
          for (int j = 0; j < 4; ++j)
            orow[colbase + j * 16 + ccol] = acc[i][j][r];
        }
      }
    }
  }
}

extern "C" void kernel_launch(void* const* d_in, const int* in_sizes, int n_in,
                              void* d_out, int out_size, void* d_ws, size_t ws_size,
                              hipStream_t stream) {
  const float* x      = (const float*)d_in[0];   // [T, D] fp32
  const float* logits = (const float*)d_in[1];   // [T, E] fp32
  const float* w1     = (const float*)d_in[2];   // [E, F, D] fp32
  const float* w2     = (const float*)d_in[3];   // [E, D, F] fp32
  float* out = (float*)d_out;                    // [T, D] fp32

  char* ws = (char*)d_ws;
  int* counts  = (int*)(ws + 0);
  int* offsets = (int*)(ws + 64);
  int* cursors = (int*)(ws + 128);
  int* tile_e  = (int*)(ws + 256);    // 72 ints
  int* tile_rb = (int*)(ws + 1024);   // 72 ints
  int* ntiles  = (int*)(ws + 2048);
  int* assign  = (int*)(ws + 4096);
  int* perm    = (int*)(ws + 4096 + T_TOKENS * 4);
  size_t p = 4096 + (size_t)2 * T_TOKENS * 4;
  p = (p + 255) & ~(size_t)255;
  unsigned short* Xg  = (unsigned short*)(ws + p); p += (size_t)T_TOKENS * DDIM * 2;
  unsigned short* W1b = (unsigned short*)(ws + p); p += (size_t)NEXP * FDIM * DDIM * 2;
  unsigned short* W2b = (unsigned short*)(ws + p); p += (size_t)NEXP * DDIM * FDIM * 2;
  unsigned short* Hb  = (unsigned short*)(ws + p); p += (size_t)T_TOKENS * FDIM * 2;
  if (ws_size < p) return;  // ~369 MB required

  // opt-in to >64KB dynamic LDS (72 KiB per block, 2 blocks/CU)
  hipFuncSetAttribute(reinterpret_cast<const void*>(k_gemm<true>),
                      hipFuncAttributeMaxDynamicSharedMemorySize, 73728);
  hipFuncSetAttribute(reinterpret_cast<const void*>(k_gemm<false>),
                      hipFuncAttributeMaxDynamicSharedMemorySize, 73728);

  hipMemsetAsync(ws, 0, 4096, stream);  // counts + cursors + tables
  k_assign<<<T_TOKENS / 256, 256, 0, stream>>>(logits, assign, counts);
  k_scan<<<1, 64, 0, stream>>>(counts, offsets, tile_e, tile_rb, ntiles);
  k_place<<<T_TOKENS / 256, 256, 0, stream>>>(assign, offsets, cursors, perm);
  k_gather_x<<<2048, 256, 0, stream>>>(x, perm, Xg);
  int n4 = NEXP * FDIM * (DDIM / 4);
  k_cast2<<<2048, 256, 0, stream>>>(w1, w2, W1b, W2b, n4);
  k_gemm<true><<<dim3(FDIM / 256, MAXTILES), 512, 73728, stream>>>(
      Xg, W1b, Hb, nullptr, offsets, counts, perm, tile_e, tile_rb, ntiles);
  k_gemm<false><<<dim3(DDIM / 256, MAXTILES), 512, 73728, stream>>>(
      Hb, W2b, nullptr, out, offsets, counts, perm, tile_e, tile_rb, ntiles);
}